// Round 6
// baseline (181.268 us; speedup 1.0000x reference)
//
#include <hip/hip_runtime.h>
#include <math.h>

// Problem constants (fixed by reference)
#define B_ 2
#define H_ 16
#define L_ 4096
#define D_ 128
#define F_ 64
#define F2_ 128
#define S_ 64
#define N_ 64
#define BH_ 32
#define NBT_ 2048
#define EPS_ 1e-6f
#define SCALING_ 0.08838834764831845f  // 128^-0.5

typedef float f32x4 __attribute__((ext_vector_type(4)));
typedef short s16x8 __attribute__((ext_vector_type(8)));

#define MFMA(a, b, c) __builtin_amdgcn_mfma_f32_16x16x32_bf16(a, b, c, 0, 0, 0)

__device__ __forceinline__ short f2bf(float f) {
  unsigned u = __float_as_uint(f);
  u += 0x7fffu + ((u >> 16) & 1u);   // RNE
  return (short)(u >> 16);
}
__device__ __forceinline__ float bf2f(short s) {
  return __uint_as_float(((unsigned)(unsigned short)s) << 16);
}

// 8 consecutive fp32 -> bf16 fragment
__device__ __forceinline__ s16x8 frag_f32(const float* p) {
  f32x4 a = *(const f32x4*)p;
  f32x4 b = *(const f32x4*)(p + 4);
  s16x8 r;
  r[0] = f2bf(a[0]); r[1] = f2bf(a[1]); r[2] = f2bf(a[2]); r[3] = f2bf(a[3]);
  r[4] = f2bf(b[0]); r[5] = f2bf(b[1]); r[6] = f2bf(b[2]); r[7] = f2bf(b[3]);
  return r;
}

// XOR swizzle: byte ^= (row&7)<<4 within a row (G4 fix for 128/256B strides)
__device__ __forceinline__ s16x8 lds_frag(const short* lds, int row, int rowBytes, int colByte) {
  int byte = row * rowBytes + (colByte ^ ((row & 7) << 4));
  return *(const s16x8*)((const char*)lds + byte);
}
__device__ __forceinline__ void lds_w16(short* lds, int row, int rowBytes, int colByte, short v) {
  int byte = row * rowBytes + (colByte ^ ((row & 7) << 4));
  *(short*)((char*)lds + byte) = v;
}

// async global->LDS, 16B per lane (dest = wave-uniform base + lane*16)
__device__ __forceinline__ void gld_lds16(const void* gsrc, void* ldst) {
  __builtin_amdgcn_global_load_lds(
      (const __attribute__((address_space(1))) unsigned int*)gsrc,
      (__attribute__((address_space(3))) unsigned int*)ldst, 16, 0, 0);
}

// ---------------------------------------------------------------------------
// prep: blocks [0,NBT_) -> VT[blk][d][t] bf16, swizzle-baked layout.
//       blocks [NBT_, NBT_+H_) -> Wt[h][f][d] bf16 (transposed).
// ---------------------------------------------------------------------------
__global__ __launch_bounds__(256)
void bslh_prep(const float* __restrict__ V, const float* __restrict__ W,
               short* __restrict__ VT, short* __restrict__ Wt)
{
  __shared__ float sv[S_][D_ + 4];
  const int tid = threadIdx.x;

  if (blockIdx.x >= NBT_) {
    const int h = blockIdx.x - NBT_;
    const int f = tid & 63, gq = tid >> 6;
    const float* Wh = W + (size_t)h * D_ * F_;
    short* Wo = Wt + (size_t)h * F_ * D_ + (size_t)f * D_ + gq * 32;
    short buf[32];
#pragma unroll
    for (int j = 0; j < 32; ++j) buf[j] = f2bf(Wh[(size_t)(gq * 32 + j) * F_ + f]);
#pragma unroll
    for (int j2 = 0; j2 < 4; ++j2) {
      s16x8 v;
#pragma unroll
      for (int e = 0; e < 8; ++e) v[e] = buf[j2 * 8 + e];
      *(s16x8*)(Wo + j2 * 8) = v;
    }
    return;
  }

  const int blk = blockIdx.x;
  const float4* gv = (const float4*)(V + (size_t)blk * S_ * D_);
#pragma unroll
  for (int ii = 0; ii < 8; ++ii) {
    int i = tid + 256 * ii;
    int t = i >> 5, c = (i & 31) * 4;
    *(float4*)&sv[t][c] = gv[i];
  }
  __syncthreads();
  const int d = tid >> 1, half = tid & 1;
  char* out = (char*)(VT + (size_t)blk * (D_ * S_)) + d * 128;
#pragma unroll
  for (int j2 = 0; j2 < 4; ++j2) {
    s16x8 v;
#pragma unroll
    for (int e = 0; e < 8; ++e) v[e] = f2bf(sv[half * 32 + j2 * 8 + e][d]);
    *(s16x8*)(out + ((half * 64 + j2 * 16) ^ ((d & 7) << 4))) = v;
  }
}

// ---------------------------------------------------------------------------
// phase1: u = k@W (MFMA), phi_k -> phiT (LDS, swizzled);
// dSt[d][f] = sum_s v[s][d]*phi[s][f] (A = staged VT, B = phiT);
// St written via LDS repack -> fully coalesced dwordx4, swizzle-baked layout.
// ---------------------------------------------------------------------------
__global__ __launch_bounds__(256, 3)
void bslh_phase1(const float* __restrict__ K, const short* __restrict__ VT,
                 const short* __restrict__ Wt, short* __restrict__ dSt,
                 float* __restrict__ dZ)
{
  __shared__ __align__(16) char lds[32 * 1024];
  short* phiT = (short*)lds;              // 16KB [128 rows][128B] swizzled
  short* VTs = (short*)(lds + 16384);     // 16KB staged VT (baked layout)
  // after MFMA section the whole 32KB is reused as the St staging image

  const int blk = blockIdx.x;
  const int bh = blk / N_;
  const int h = bh % H_;
  const int tid = threadIdx.x;
  const int wave = tid >> 6, lane = tid & 63;
  const int rl = lane & 15, g = lane >> 4, kl = g * 8;
  const int r0 = wave * 16;

  const short* VTb = VT + (size_t)blk * (D_ * S_);
#pragma unroll
  for (int i = 0; i < 4; ++i)
    gld_lds16((const char*)VTb + tid * 16 + i * 4096,
              lds + 16384 + tid * 16 + i * 4096);

  const float* Kb = K + (size_t)blk * (S_ * D_);
  const short* Wh = Wt + (size_t)h * (F_ * D_);
  const f32x4 z4 = {0.f, 0.f, 0.f, 0.f};

  // ---- u = k @ W ----
  f32x4 uacc[4] = {z4, z4, z4, z4};
  for (int ks = 0; ks < 4; ++ks) {
    s16x8 a = frag_f32(Kb + (size_t)(r0 + rl) * D_ + ks * 32 + kl);
#pragma unroll
    for (int tn = 0; tn < 4; ++tn) {
      s16x8 b = *(const s16x8*)(Wh + (size_t)(tn * 16 + rl) * D_ + ks * 32 + kl);
      uacc[tn] = MFMA(a, b, uacc[tn]);
    }
  }

  // ---- phi = [softmax(u), softmax(-u)] -> phiT (transposed, swizzled) ----
#pragma unroll
  for (int reg = 0; reg < 4; ++reg) {
    float mx = -1e30f, mn = 1e30f;
#pragma unroll
    for (int tn = 0; tn < 4; ++tn) {
      mx = fmaxf(mx, uacc[tn][reg]);
      mn = fminf(mn, uacc[tn][reg]);
    }
#pragma unroll
    for (int o = 1; o <= 8; o <<= 1) {
      mx = fmaxf(mx, __shfl_xor(mx, o, 64));
      mn = fminf(mn, __shfl_xor(mn, o, 64));
    }
    float ep[4], em[4], sp = 0.f, sm = 0.f;
#pragma unroll
    for (int tn = 0; tn < 4; ++tn) {
      ep[tn] = __expf(uacc[tn][reg] - mx); sp += ep[tn];
      em[tn] = __expf(mn - uacc[tn][reg]); sm += em[tn];
    }
#pragma unroll
    for (int o = 1; o <= 8; o <<= 1) {
      sp += __shfl_xor(sp, o, 64);
      sm += __shfl_xor(sm, o, 64);
    }
    const float rp = 1.f / sp, rm = 1.f / sm;
    const int srow = r0 + g * 4 + reg;
#pragma unroll
    for (int tn = 0; tn < 4; ++tn) {
      int f = tn * 16 + rl;
      lds_w16(phiT, f,      2 * S_, srow * 2, f2bf(ep[tn] * rp));
      lds_w16(phiT, f + 64, 2 * S_, srow * 2, f2bf(em[tn] * rm));
    }
  }
  __syncthreads();   // phiT visible; VT staging drained

  // ---- dZ[f] = sum_s phi[s][f] ----
  {
    const int f = tid >> 1, half = tid & 1;
    float z = 0.f;
#pragma unroll
    for (int j2 = 0; j2 < 4; ++j2) {
      s16x8 v = lds_frag(phiT, f, 2 * S_, (half * 32 + j2 * 8) * 2);
#pragma unroll
      for (int e = 0; e < 8; ++e) z += bf2f(v[e]);
    }
    z += __shfl_xor(z, 1, 64);
    if (half == 0) dZ[(size_t)blk * F2_ + f] = z;
  }

  // ---- dSt[d][f] ; wave owns d-rows 32w..32w+31 ----
  f32x4 acc[2][8];
#pragma unroll
  for (int tm = 0; tm < 2; ++tm)
#pragma unroll
    for (int tn = 0; tn < 8; ++tn) acc[tm][tn] = z4;

  for (int ks = 0; ks < 2; ++ks) {
    s16x8 a[2];
#pragma unroll
    for (int tm = 0; tm < 2; ++tm)
      a[tm] = lds_frag(VTs, wave * 32 + tm * 16 + rl, 2 * S_, (ks * 32 + kl) * 2);
#pragma unroll
    for (int tn = 0; tn < 8; ++tn) {
      s16x8 b = lds_frag(phiT, tn * 16 + rl, 2 * S_, (ks * 32 + kl) * 2);
#pragma unroll
      for (int tm = 0; tm < 2; ++tm)
        acc[tm][tn] = MFMA(a[tm], b, acc[tm][tn]);
    }
  }
  __syncthreads();   // all phiT/VTs reads done; reuse lds as St image

  // ---- pack acc into LDS St image (swizzle-baked), then coalesced store ----
  short* Stb = (short*)lds;
#pragma unroll
  for (int tm = 0; tm < 2; ++tm)
#pragma unroll
    for (int tn = 0; tn < 8; ++tn)
#pragma unroll
      for (int reg = 0; reg < 4; ++reg) {
        float v0 = acc[tm][tn][reg];
        float v1 = __shfl_xor(v0, 1, 64);
        if (!(lane & 1)) {
          int drow = wave * 32 + tm * 16 + g * 4 + reg;
          int fcol = tn * 16 + rl;
          unsigned pk = (unsigned)(unsigned short)f2bf(v0) |
                        ((unsigned)(unsigned short)f2bf(v1) << 16);
          int byte = drow * 256 + ((fcol * 2) ^ ((drow & 7) << 4));
          *(unsigned*)((char*)Stb + byte) = pk;
        }
      }
  __syncthreads();

  float4* dst = (float4*)(dSt + (size_t)blk * (F2_ * D_));
  const float4* srcl = (const float4*)lds;
#pragma unroll
  for (int i = 0; i < 8; ++i) dst[tid + 256 * i] = srcl[tid + 256 * i];
}

// ---------------------------------------------------------------------------
// scan: blocks [0,256) -> exclusive prefix of St chunks (layout-agnostic);
//       blocks [256,260) -> exclusive prefix of dZ.
// ---------------------------------------------------------------------------
__global__ __launch_bounds__(256)
void bslh_scan(short* __restrict__ St, float4* __restrict__ dZ4)
{
  const int tid = threadIdx.x;
  if (blockIdx.x < 256) {
    const int idx = blockIdx.x * 256 + tid;      // 65536 threads
    const int bh = idx >> 11;
    const int rem = idx & 2047;
    short* p = St + (size_t)bh * N_ * (F2_ * D_) + (size_t)rem * 8;
    float run[8] = {0.f, 0.f, 0.f, 0.f, 0.f, 0.f, 0.f, 0.f};
    for (int n = 0; n < N_; ++n) {
      s16x8 v = *(const s16x8*)p;
      s16x8 o;
#pragma unroll
      for (int e = 0; e < 8; ++e) {
        o[e] = f2bf(run[e]);
        run[e] += bf2f(v[e]);
      }
      *(s16x8*)p = o;
      p += F2_ * D_;
    }
  } else {
    const int idx = (blockIdx.x - 256) * 256 + tid;  // 1024 threads
    const int bh = idx >> 5, e = idx & 31;
    float4* p = dZ4 + (size_t)bh * N_ * 32 + e;
    float4 run = make_float4(0.f, 0.f, 0.f, 0.f);
    for (int n = 0; n < N_; ++n) {
      float4 v = p[(size_t)n * 32];
      p[(size_t)n * 32] = run;
      run.x += v.x; run.y += v.y; run.z += v.z; run.w += v.w;
    }
  }
}

// ---------------------------------------------------------------------------
// phase3: stage St+VT via global_load_lds (hidden under u/softmax/scores);
// u=q@W -> phi_q; cl=(1-w)/max(phi·Z,eps); scores (reusing Q A-frags) ->
// P*w; acc = (phi @ St)*cl + P @ V; store.
// ---------------------------------------------------------------------------
__global__ __launch_bounds__(256, 2)
void bslh_phase3(const float* __restrict__ Q, const float* __restrict__ K,
                 const short* __restrict__ VT, const short* __restrict__ Wt,
                 const short* __restrict__ St, const float* __restrict__ Zp,
                 const float* __restrict__ alphap, float* __restrict__ Out)
{
  __shared__ __align__(16) short Ssm[F2_ * D_];  // 32KB staged St (baked swz)
  __shared__ __align__(16) short Vsm[D_ * S_];   // 16KB staged VT (baked swz)
  __shared__ __align__(16) short phi[S_ * F2_];  // 16KB [64][256B] swizzled
  __shared__ __align__(16) short Pl[S_ * S_];    // 8KB  [64][128B] swizzled
  __shared__ float clL[S_];

  const int blk = blockIdx.x;
  const int bh = blk / N_;
  const int h = bh % H_;
  const int tid = threadIdx.x;
  const int wave = tid >> 6, lane = tid & 63;
  const int rl = lane & 15, g = lane >> 4, kl = g * 8;
  const int r0 = wave * 16;

  const short* Sb = St + (size_t)blk * (F2_ * D_);
  const short* VTb = VT + (size_t)blk * (D_ * S_);
#pragma unroll
  for (int i = 0; i < 8; ++i)
    gld_lds16((const char*)Sb + tid * 16 + i * 4096,
              (char*)Ssm + tid * 16 + i * 4096);
#pragma unroll
  for (int i = 0; i < 4; ++i)
    gld_lds16((const char*)VTb + tid * 16 + i * 4096,
              (char*)Vsm + tid * 16 + i * 4096);

  const float* Qb = Q + (size_t)blk * (S_ * D_);
  const float* Kb = K + (size_t)blk * (S_ * D_);
  const short* Wh = Wt + (size_t)h * (F_ * D_);
  const float w = 1.f / (1.f + __expf(-alphap[0]));
  const f32x4 z4 = {0.f, 0.f, 0.f, 0.f};

  // ---- u = q @ W (save Q A-fragments for scores) ----
  s16x8 aq[4];
  f32x4 uacc[4] = {z4, z4, z4, z4};
  for (int ks = 0; ks < 4; ++ks) {
    aq[ks] = frag_f32(Qb + (size_t)(r0 + rl) * D_ + ks * 32 + kl);
#pragma unroll
    for (int tn = 0; tn < 4; ++tn) {
      s16x8 b = *(const s16x8*)(Wh + (size_t)(tn * 16 + rl) * D_ + ks * 32 + kl);
      uacc[tn] = MFMA(aq[ks], b, uacc[tn]);
    }
  }

  // ---- phi_q (row-major, swizzled) ----
#pragma unroll
  for (int reg = 0; reg < 4; ++reg) {
    float mx = -1e30f, mn = 1e30f;
#pragma unroll
    for (int tn = 0; tn < 4; ++tn) {
      mx = fmaxf(mx, uacc[tn][reg]);
      mn = fminf(mn, uacc[tn][reg]);
    }
#pragma unroll
    for (int o = 1; o <= 8; o <<= 1) {
      mx = fmaxf(mx, __shfl_xor(mx, o, 64));
      mn = fminf(mn, __shfl_xor(mn, o, 64));
    }
    float ep[4], em[4], sp = 0.f, sm = 0.f;
#pragma unroll
    for (int tn = 0; tn < 4; ++tn) {
      ep[tn] = __expf(uacc[tn][reg] - mx); sp += ep[tn];
      em[tn] = __expf(mn - uacc[tn][reg]); sm += em[tn];
    }
#pragma unroll
    for (int o = 1; o <= 8; o <<= 1) {
      sp += __shfl_xor(sp, o, 64);
      sm += __shfl_xor(sm, o, 64);
    }
    const float rp = 1.f / sp, rm = 1.f / sm;
    const int srow = r0 + g * 4 + reg;
#pragma unroll
    for (int tn = 0; tn < 4; ++tn) {
      int f = tn * 16 + rl;
      lds_w16(phi, srow, 2 * F2_, f * 2,        f2bf(ep[tn] * rp));
      lds_w16(phi, srow, 2 * F2_, (f + 64) * 2, f2bf(em[tn] * rm));
    }
  }
  __syncthreads();   // phi visible; Ssm/Vsm staging drained

  // ---- cl[row] = (1-w)/max(phi·Zprefix, eps) ----
  if (tid < 64) {
    const float* Zb = Zp + (size_t)blk * F2_;
    float den = 0.f;
#pragma unroll
    for (int j2 = 0; j2 < 16; ++j2) {
      s16x8 v = lds_frag(phi, tid, 2 * F2_, j2 * 16);
#pragma unroll
      for (int e = 0; e < 8; ++e) den += bf2f(v[e]) * Zb[j2 * 8 + e];
    }
    clL[tid] = (1.f - w) / fmaxf(den, EPS_);
  }

  // ---- scores = q @ k^T (A-frags reused), softmax, P*w -> Pl ----
  f32x4 sacc[4] = {z4, z4, z4, z4};
  for (int ks = 0; ks < 4; ++ks) {
#pragma unroll
    for (int tn = 0; tn < 4; ++tn) {
      s16x8 b = frag_f32(Kb + (size_t)(tn * 16 + rl) * D_ + ks * 32 + kl);
      sacc[tn] = MFMA(aq[ks], b, sacc[tn]);
    }
  }
#pragma unroll
  for (int reg = 0; reg < 4; ++reg) {
    float mx = -1e30f;
#pragma unroll
    for (int tn = 0; tn < 4; ++tn) {
      sacc[tn][reg] *= SCALING_;
      mx = fmaxf(mx, sacc[tn][reg]);
    }
#pragma unroll
    for (int o = 1; o <= 8; o <<= 1) mx = fmaxf(mx, __shfl_xor(mx, o, 64));
    float e_[4], sum = 0.f;
#pragma unroll
    for (int tn = 0; tn < 4; ++tn) {
      e_[tn] = __expf(sacc[tn][reg] - mx);
      sum += e_[tn];
    }
#pragma unroll
    for (int o = 1; o <= 8; o <<= 1) sum += __shfl_xor(sum, o, 64);
    const float pw = w / sum;
    const int srow = r0 + g * 4 + reg;
#pragma unroll
    for (int tn = 0; tn < 4; ++tn)
      lds_w16(Pl, srow, 2 * S_, (tn * 16 + rl) * 2, f2bf(e_[tn] * pw));
  }
  __syncthreads();

  // ---- acc = phi @ St (from LDS), scale by cl, acc += P @ V (from LDS) ----
  f32x4 acc[8];
#pragma unroll
  for (int tn = 0; tn < 8; ++tn) acc[tn] = z4;

  for (int ks = 0; ks < 4; ++ks) {
    s16x8 a = lds_frag(phi, r0 + rl, 2 * F2_, (ks * 32 + kl) * 2);
#pragma unroll
    for (int tn = 0; tn < 8; ++tn) {
      s16x8 b = lds_frag(Ssm, tn * 16 + rl, 2 * F2_, (ks * 32 + kl) * 2);
      acc[tn] = MFMA(a, b, acc[tn]);
    }
  }
  float cl[4];
#pragma unroll
  for (int reg = 0; reg < 4; ++reg) cl[reg] = clL[r0 + g * 4 + reg];
#pragma unroll
  for (int tn = 0; tn < 8; ++tn)
#pragma unroll
    for (int reg = 0; reg < 4; ++reg) acc[tn][reg] *= cl[reg];

  for (int ks = 0; ks < 2; ++ks) {
    s16x8 a = lds_frag(Pl, r0 + rl, 2 * S_, (ks * 32 + kl) * 2);
#pragma unroll
    for (int tn = 0; tn < 8; ++tn) {
      s16x8 b = lds_frag(Vsm, tn * 16 + rl, 2 * S_, (ks * 32 + kl) * 2);
      acc[tn] = MFMA(a, b, acc[tn]);
    }
  }

  // ---- store ----
  float* Ob = Out + (size_t)blk * (S_ * D_);
#pragma unroll
  for (int tn = 0; tn < 8; ++tn)
#pragma unroll
    for (int reg = 0; reg < 4; ++reg) {
      int srow = r0 + g * 4 + reg;
      Ob[(size_t)srow * D_ + tn * 16 + rl] = acc[tn][reg];
    }
}

// ---------------------------------------------------------------------------
extern "C" void kernel_launch(void* const* d_in, const int* in_sizes, int n_in,
                              void* d_out, int out_size, void* d_ws, size_t ws_size,
                              hipStream_t stream)
{
  const float* Q = (const float*)d_in[0];
  const float* K = (const float*)d_in[1];
  const float* V = (const float*)d_in[2];
  const float* W = (const float*)d_in[3];
  const float* alpha = (const float*)d_in[4];
  float* Out = (float*)d_out;

  short* VT = (short*)d_ws;                              // 32 MiB
  short* St = VT + (size_t)NBT_ * D_ * S_;               // 64 MiB
  float* dZ = (float*)(St + (size_t)NBT_ * F2_ * D_);    // 1 MiB
  short* Wt = (short*)(dZ + (size_t)NBT_ * F2_);         // 256 KiB

  hipLaunchKernelGGL(bslh_prep, dim3(NBT_ + H_), dim3(256), 0, stream, V, W, VT, Wt);
  hipLaunchKernelGGL(bslh_phase1, dim3(NBT_), dim3(256), 0, stream, K, VT, Wt, St, dZ);
  hipLaunchKernelGGL(bslh_scan, dim3(260), dim3(256), 0, stream, St, (float4*)dZ);
  hipLaunchKernelGGL(bslh_phase3, dim3(NBT_), dim3(256), 0, stream,
                     Q, K, VT, Wt, St, dZ, alpha, Out);
}

// Round 7
// 172.581 us; speedup vs baseline: 1.0503x; 1.0503x over previous
//
#include <hip/hip_runtime.h>
#include <math.h>

// Problem constants (fixed by reference)
#define B_ 2
#define H_ 16
#define L_ 4096
#define D_ 128
#define F_ 64
#define F2_ 128
#define S_ 64
#define N_ 64
#define BH_ 32
#define NBT_ 2048
#define EPS_ 1e-6f
#define SCALING_ 0.08838834764831845f  // 128^-0.5

typedef float f32x4 __attribute__((ext_vector_type(4)));
typedef short s16x8 __attribute__((ext_vector_type(8)));
typedef short s16x4 __attribute__((ext_vector_type(4)));

#define MFMA(a, b, c) __builtin_amdgcn_mfma_f32_16x16x32_bf16(a, b, c, 0, 0, 0)

__device__ __forceinline__ short f2bf(float f) {
  unsigned u = __float_as_uint(f);
  u += 0x7fffu + ((u >> 16) & 1u);   // RNE
  return (short)(u >> 16);
}
__device__ __forceinline__ float bf2f(short s) {
  return __uint_as_float(((unsigned)(unsigned short)s) << 16);
}

// 8 consecutive fp32 -> bf16 fragment
__device__ __forceinline__ s16x8 frag_f32(const float* p) {
  f32x4 a = *(const f32x4*)p;
  f32x4 b = *(const f32x4*)(p + 4);
  s16x8 r;
  r[0] = f2bf(a[0]); r[1] = f2bf(a[1]); r[2] = f2bf(a[2]); r[3] = f2bf(a[3]);
  r[4] = f2bf(b[0]); r[5] = f2bf(b[1]); r[6] = f2bf(b[2]); r[7] = f2bf(b[3]);
  return r;
}

// XOR swizzle: byte ^= (row&7)<<4 within a row. Used for LDS bank-conflict
// avoidance AND baked into the St/VT global layouts (so LDS and global
// fragment reads share one address formula).
__device__ __forceinline__ s16x8 swz_frag(const short* base, int row, int rowBytes, int colByte) {
  int byte = row * rowBytes + (colByte ^ ((row & 7) << 4));
  return *(const s16x8*)((const char*)base + byte);
}
__device__ __forceinline__ void lds_w16(short* lds, int row, int rowBytes, int colByte, short v) {
  int byte = row * rowBytes + (colByte ^ ((row & 7) << 4));
  *(short*)((char*)lds + byte) = v;
}

// ---------------------------------------------------------------------------
// prep_w: Wt[h][f][d] bf16 (transposed) so B-fragments of u=x@W are contiguous.
// ---------------------------------------------------------------------------
__global__ __launch_bounds__(256)
void prep_w(const float* __restrict__ W, short* __restrict__ Wt)
{
  const int h = blockIdx.x;
  const int tid = threadIdx.x;
  const int f = tid & 63, gq = tid >> 6;
  const float* Wh = W + (size_t)h * D_ * F_;
  short* Wo = Wt + (size_t)h * F_ * D_ + (size_t)f * D_ + gq * 32;
  short buf[32];
#pragma unroll
  for (int j = 0; j < 32; ++j) buf[j] = f2bf(Wh[(size_t)(gq * 32 + j) * F_ + f]);
#pragma unroll
  for (int j2 = 0; j2 < 4; ++j2) {
    s16x8 v;
#pragma unroll
    for (int e = 0; e < 8; ++e) v[e] = buf[j2 * 8 + e];
    *(s16x8*)(Wo + j2 * 8) = v;
  }
}

// ---------------------------------------------------------------------------
// phase1 (fused V-transpose): stage V -> VTs LDS image (bf16, baked swizzle);
// u = k@W (MFMA); phi_k -> phiT (LDS, swizzled); dZ colsums; dSt (MFMA,
// A=VTs, B=phiT); write VT global (coalesced) for phase3; repack acc into
// LDS St image and store coalesced dwordx4.
// ---------------------------------------------------------------------------
__global__ __launch_bounds__(256, 3)
void bslh_phase1(const float* __restrict__ K, const float* __restrict__ V,
                 const short* __restrict__ Wt, short* __restrict__ VT,
                 short* __restrict__ dSt, float* __restrict__ dZ)
{
  __shared__ __align__(16) char lds[32 * 1024];
  short* phiT = (short*)lds;              // 16KB [128 f][128B] swizzled
  short* VTs = (short*)(lds + 16384);     // 16KB [128 d][128B] baked layout
  // after the MFMA section the whole 32KB is reused as the St staging image

  const int blk = blockIdx.x;
  const int bh = blk / N_;
  const int h = bh % H_;
  const int tid = threadIdx.x;
  const int wave = tid >> 6, lane = tid & 63;
  const int rl = lane & 15, g = lane >> 4, kl = g * 8;
  const int r0 = wave * 16;

  // ---- stage V -> VTs (transpose + bf16). lanes tid, tid^32 hold rows s,
  // s+1 of the same col range; even-s lane packs the pair -> 4B write.
  {
    const float4* gv = (const float4*)(V + (size_t)blk * S_ * D_);
#pragma unroll
    for (int ii = 0; ii < 8; ++ii) {
      int idx = tid + 256 * ii;
      int s = idx >> 5, c = (idx & 31) * 4;
      float4 v = gv[idx];
      float o0 = __shfl_xor(v.x, 32, 64);
      float o1 = __shfl_xor(v.y, 32, 64);
      float o2 = __shfl_xor(v.z, 32, 64);
      float o3 = __shfl_xor(v.w, 32, 64);
      if (!(tid & 32)) {
        float m[4] = {v.x, v.y, v.z, v.w};
        float o[4] = {o0, o1, o2, o3};
#pragma unroll
        for (int j = 0; j < 4; ++j) {
          int d = c + j;
          unsigned pk = (unsigned)(unsigned short)f2bf(m[j]) |
                        ((unsigned)(unsigned short)f2bf(o[j]) << 16);
          int byte = d * 128 + ((s * 2) ^ ((d & 7) << 4));
          *(unsigned*)((char*)VTs + byte) = pk;
        }
      }
    }
  }

  const float* Kb = K + (size_t)blk * (S_ * D_);
  const short* Wh = Wt + (size_t)h * (F_ * D_);
  const f32x4 z4 = {0.f, 0.f, 0.f, 0.f};

  // ---- u = k @ W ----
  f32x4 uacc[4] = {z4, z4, z4, z4};
  for (int ks = 0; ks < 4; ++ks) {
    s16x8 a = frag_f32(Kb + (size_t)(r0 + rl) * D_ + ks * 32 + kl);
#pragma unroll
    for (int tn = 0; tn < 4; ++tn) {
      s16x8 b = *(const s16x8*)(Wh + (size_t)(tn * 16 + rl) * D_ + ks * 32 + kl);
      uacc[tn] = MFMA(a, b, uacc[tn]);
    }
  }

  // ---- phi = [softmax(u), softmax(-u)] -> phiT (transposed, swizzled) ----
#pragma unroll
  for (int reg = 0; reg < 4; ++reg) {
    float mx = -1e30f, mn = 1e30f;
#pragma unroll
    for (int tn = 0; tn < 4; ++tn) {
      mx = fmaxf(mx, uacc[tn][reg]);
      mn = fminf(mn, uacc[tn][reg]);
    }
#pragma unroll
    for (int o = 1; o <= 8; o <<= 1) {
      mx = fmaxf(mx, __shfl_xor(mx, o, 64));
      mn = fminf(mn, __shfl_xor(mn, o, 64));
    }
    float ep[4], em[4], sp = 0.f, sm = 0.f;
#pragma unroll
    for (int tn = 0; tn < 4; ++tn) {
      ep[tn] = __expf(uacc[tn][reg] - mx); sp += ep[tn];
      em[tn] = __expf(mn - uacc[tn][reg]); sm += em[tn];
    }
#pragma unroll
    for (int o = 1; o <= 8; o <<= 1) {
      sp += __shfl_xor(sp, o, 64);
      sm += __shfl_xor(sm, o, 64);
    }
    const float rp = 1.f / sp, rm = 1.f / sm;
    const int srow = r0 + g * 4 + reg;
#pragma unroll
    for (int tn = 0; tn < 4; ++tn) {
      int f = tn * 16 + rl;
      lds_w16(phiT, f,      2 * S_, srow * 2, f2bf(ep[tn] * rp));
      lds_w16(phiT, f + 64, 2 * S_, srow * 2, f2bf(em[tn] * rm));
    }
  }
  __syncthreads();   // phiT + VTs images complete

  // ---- write VT global (coalesced float4 copy of the 16KB image) ----
  {
    float4* dst = (float4*)(VT + (size_t)blk * (D_ * S_));
    const float4* src = (const float4*)VTs;
#pragma unroll
    for (int i = 0; i < 4; ++i) dst[tid + 256 * i] = src[tid + 256 * i];
  }

  // ---- dZ[f] = sum_s phi[s][f] ----
  {
    const int f = tid >> 1, half = tid & 1;
    float z = 0.f;
#pragma unroll
    for (int j2 = 0; j2 < 4; ++j2) {
      s16x8 v = swz_frag(phiT, f, 2 * S_, (half * 32 + j2 * 8) * 2);
#pragma unroll
      for (int e = 0; e < 8; ++e) z += bf2f(v[e]);
    }
    z += __shfl_xor(z, 1, 64);
    if (half == 0) dZ[(size_t)blk * F2_ + f] = z;
  }

  // ---- dSt[d][f] = sum_s v[s][d]*phi[s][f]; wave owns d-rows 32w..32w+31 ----
  f32x4 acc[2][8];
#pragma unroll
  for (int tm = 0; tm < 2; ++tm)
#pragma unroll
    for (int tn = 0; tn < 8; ++tn) acc[tm][tn] = z4;

  for (int ks = 0; ks < 2; ++ks) {
    s16x8 a[2];
#pragma unroll
    for (int tm = 0; tm < 2; ++tm)
      a[tm] = swz_frag(VTs, wave * 32 + tm * 16 + rl, 2 * S_, (ks * 32 + kl) * 2);
#pragma unroll
    for (int tn = 0; tn < 8; ++tn) {
      s16x8 b = swz_frag(phiT, tn * 16 + rl, 2 * S_, (ks * 32 + kl) * 2);
#pragma unroll
      for (int tm = 0; tm < 2; ++tm)
        acc[tm][tn] = MFMA(a[tm], b, acc[tm][tn]);
    }
  }
  __syncthreads();   // all phiT/VTs reads done; reuse lds as St image

  // ---- pack acc into LDS St image (baked swizzle), coalesced store ----
  short* Stb = (short*)lds;
#pragma unroll
  for (int tm = 0; tm < 2; ++tm)
#pragma unroll
    for (int tn = 0; tn < 8; ++tn)
#pragma unroll
      for (int reg = 0; reg < 4; ++reg) {
        float v0 = acc[tm][tn][reg];
        float v1 = __shfl_xor(v0, 1, 64);
        if (!(lane & 1)) {
          int drow = wave * 32 + tm * 16 + g * 4 + reg;
          int fcol = tn * 16 + rl;
          unsigned pk = (unsigned)(unsigned short)f2bf(v0) |
                        ((unsigned)(unsigned short)f2bf(v1) << 16);
          int byte = drow * 256 + ((fcol * 2) ^ ((drow & 7) << 4));
          *(unsigned*)((char*)Stb + byte) = pk;
        }
      }
  __syncthreads();

  float4* dst = (float4*)(dSt + (size_t)blk * (F2_ * D_));
  const float4* srcl = (const float4*)lds;
#pragma unroll
  for (int i = 0; i < 8; ++i) dst[tid + 256 * i] = srcl[tid + 256 * i];
}

// ---------------------------------------------------------------------------
// scan: blocks [0,512) -> exclusive prefix of St in 4-short chunks
// (layout-agnostic: XOR permutes 16B units, we scan aligned 8B sub-units);
// blocks [512,516) -> exclusive prefix of dZ.
// ---------------------------------------------------------------------------
__global__ __launch_bounds__(256)
void bslh_scan(short* __restrict__ St, float4* __restrict__ dZ4)
{
  const int tid = threadIdx.x;
  if (blockIdx.x < 512) {
    const int idx = blockIdx.x * 256 + tid;      // 131072 threads
    const int bh = idx >> 12;
    const int rem = idx & 4095;
    short* p = St + (size_t)bh * N_ * (F2_ * D_) + (size_t)rem * 4;
    float run[4] = {0.f, 0.f, 0.f, 0.f};
    for (int n = 0; n < N_; ++n) {
      s16x4 v = *(const s16x4*)p;
      s16x4 o;
#pragma unroll
      for (int e = 0; e < 4; ++e) {
        o[e] = f2bf(run[e]);
        run[e] += bf2f(v[e]);
      }
      *(s16x4*)p = o;
      p += F2_ * D_;
    }
  } else {
    const int idx = (blockIdx.x - 512) * 256 + tid;  // 1024 threads
    const int bh = idx >> 5, e = idx & 31;
    float4* p = dZ4 + (size_t)bh * N_ * 32 + e;
    float4 run = make_float4(0.f, 0.f, 0.f, 0.f);
    for (int n = 0; n < N_; ++n) {
      float4 v = p[(size_t)n * 32];
      p[(size_t)n * 32] = run;
      run.x += v.x; run.y += v.y; run.z += v.z; run.w += v.w;
    }
  }
}

// ---------------------------------------------------------------------------
// phase3 (no St/VT staging — direct global fragment reads, high occupancy):
// u=q@W -> phi_q (LDS); cl=(1-w)/max(phi·Z,eps); scores (Q A-frags reused)
// -> P*w (LDS); acc = (phi @ St)*cl + P @ V; store.
// ---------------------------------------------------------------------------
__global__ __launch_bounds__(256, 4)
void bslh_phase3(const float* __restrict__ Q, const float* __restrict__ K,
                 const short* __restrict__ VT, const short* __restrict__ Wt,
                 const short* __restrict__ St, const float* __restrict__ Zp,
                 const float* __restrict__ alphap, float* __restrict__ Out)
{
  __shared__ __align__(16) short phi[S_ * F2_];  // 16KB [64][256B] swizzled
  __shared__ __align__(16) short Pl[S_ * S_];    // 8KB  [64][128B] swizzled
  __shared__ float clL[S_];

  const int blk = blockIdx.x;
  const int bh = blk / N_;
  const int h = bh % H_;
  const int tid = threadIdx.x;
  const int wave = tid >> 6, lane = tid & 63;
  const int rl = lane & 15, g = lane >> 4, kl = g * 8;
  const int r0 = wave * 16;

  const short* Sb = St + (size_t)blk * (F2_ * D_);
  const short* VTb = VT + (size_t)blk * (D_ * S_);
  const float* Qb = Q + (size_t)blk * (S_ * D_);
  const float* Kb = K + (size_t)blk * (S_ * D_);
  const short* Wh = Wt + (size_t)h * (F_ * D_);
  const float w = 1.f / (1.f + __expf(-alphap[0]));
  const f32x4 z4 = {0.f, 0.f, 0.f, 0.f};

  // ---- u = q @ W (save Q A-fragments for scores) ----
  s16x8 aq[4];
  f32x4 uacc[4] = {z4, z4, z4, z4};
  for (int ks = 0; ks < 4; ++ks) {
    aq[ks] = frag_f32(Qb + (size_t)(r0 + rl) * D_ + ks * 32 + kl);
#pragma unroll
    for (int tn = 0; tn < 4; ++tn) {
      s16x8 b = *(const s16x8*)(Wh + (size_t)(tn * 16 + rl) * D_ + ks * 32 + kl);
      uacc[tn] = MFMA(aq[ks], b, uacc[tn]);
    }
  }

  // ---- phi_q (row-major, swizzled) ----
#pragma unroll
  for (int reg = 0; reg < 4; ++reg) {
    float mx = -1e30f, mn = 1e30f;
#pragma unroll
    for (int tn = 0; tn < 4; ++tn) {
      mx = fmaxf(mx, uacc[tn][reg]);
      mn = fminf(mn, uacc[tn][reg]);
    }
#pragma unroll
    for (int o = 1; o <= 8; o <<= 1) {
      mx = fmaxf(mx, __shfl_xor(mx, o, 64));
      mn = fminf(mn, __shfl_xor(mn, o, 64));
    }
    float ep[4], em[4], sp = 0.f, sm = 0.f;
#pragma unroll
    for (int tn = 0; tn < 4; ++tn) {
      ep[tn] = __expf(uacc[tn][reg] - mx); sp += ep[tn];
      em[tn] = __expf(mn - uacc[tn][reg]); sm += em[tn];
    }
#pragma unroll
    for (int o = 1; o <= 8; o <<= 1) {
      sp += __shfl_xor(sp, o, 64);
      sm += __shfl_xor(sm, o, 64);
    }
    const float rp = 1.f / sp, rm = 1.f / sm;
    const int srow = r0 + g * 4 + reg;
#pragma unroll
    for (int tn = 0; tn < 4; ++tn) {
      int f = tn * 16 + rl;
      lds_w16(phi, srow, 2 * F2_, f * 2,        f2bf(ep[tn] * rp));
      lds_w16(phi, srow, 2 * F2_, (f + 64) * 2, f2bf(em[tn] * rm));
    }
  }
  __syncthreads();

  // ---- cl[row] = (1-w)/max(phi·Zprefix, eps) ----
  if (tid < 64) {
    const float* Zb = Zp + (size_t)blk * F2_;
    float den = 0.f;
#pragma unroll
    for (int j2 = 0; j2 < 16; ++j2) {
      s16x8 v = swz_frag(phi, tid, 2 * F2_, j2 * 16);
      f32x4 z0 = *(const f32x4*)(Zb + j2 * 8);
      f32x4 z1 = *(const f32x4*)(Zb + j2 * 8 + 4);
      den += bf2f(v[0]) * z0[0] + bf2f(v[1]) * z0[1] +
             bf2f(v[2]) * z0[2] + bf2f(v[3]) * z0[3] +
             bf2f(v[4]) * z1[0] + bf2f(v[5]) * z1[1] +
             bf2f(v[6]) * z1[2] + bf2f(v[7]) * z1[3];
    }
    clL[tid] = (1.f - w) / fmaxf(den, EPS_);
  }

  // ---- scores = q @ k^T (A-frags reused), softmax, P*w -> Pl ----
  f32x4 sacc[4] = {z4, z4, z4, z4};
  for (int ks = 0; ks < 4; ++ks) {
#pragma unroll
    for (int tn = 0; tn < 4; ++tn) {
      s16x8 b = frag_f32(Kb + (size_t)(tn * 16 + rl) * D_ + ks * 32 + kl);
      sacc[tn] = MFMA(aq[ks], b, sacc[tn]);
    }
  }
#pragma unroll
  for (int reg = 0; reg < 4; ++reg) {
    float mx = -1e30f;
#pragma unroll
    for (int tn = 0; tn < 4; ++tn) {
      sacc[tn][reg] *= SCALING_;
      mx = fmaxf(mx, sacc[tn][reg]);
    }
#pragma unroll
    for (int o = 1; o <= 8; o <<= 1) mx = fmaxf(mx, __shfl_xor(mx, o, 64));
    float e_[4], sum = 0.f;
#pragma unroll
    for (int tn = 0; tn < 4; ++tn) {
      e_[tn] = __expf(sacc[tn][reg] - mx);
      sum += e_[tn];
    }
#pragma unroll
    for (int o = 1; o <= 8; o <<= 1) sum += __shfl_xor(sum, o, 64);
    const float pw = w / sum;
    const int srow = r0 + g * 4 + reg;
#pragma unroll
    for (int tn = 0; tn < 4; ++tn)
      lds_w16(Pl, srow, 2 * S_, (tn * 16 + rl) * 2, f2bf(e_[tn] * pw));
  }
  __syncthreads();

  // ---- acc = phi @ St (St direct from global, baked swizzle), *cl ----
  f32x4 acc[8];
#pragma unroll
  for (int tn = 0; tn < 8; ++tn) acc[tn] = z4;

  for (int ks = 0; ks < 4; ++ks) {
    s16x8 a = swz_frag(phi, r0 + rl, 2 * F2_, (ks * 32 + kl) * 2);
#pragma unroll
    for (int tn = 0; tn < 8; ++tn) {
      s16x8 b = swz_frag(Sb, tn * 16 + rl, 2 * F2_, (ks * 32 + kl) * 2);
      acc[tn] = MFMA(a, b, acc[tn]);
    }
  }
  float cl[4];
#pragma unroll
  for (int reg = 0; reg < 4; ++reg) cl[reg] = clL[r0 + g * 4 + reg];
#pragma unroll
  for (int tn = 0; tn < 8; ++tn)
#pragma unroll
    for (int reg = 0; reg < 4; ++reg) acc[tn][reg] *= cl[reg];

  // ---- acc += P @ V (VT direct from global, baked swizzle) ----
  for (int ks = 0; ks < 2; ++ks) {
    s16x8 a = swz_frag(Pl, r0 + rl, 2 * S_, (ks * 32 + kl) * 2);
#pragma unroll
    for (int tn = 0; tn < 8; ++tn) {
      s16x8 b = swz_frag(VTb, tn * 16 + rl, 2 * S_, (ks * 32 + kl) * 2);
      acc[tn] = MFMA(a, b, acc[tn]);
    }
  }

  // ---- store ----
  float* Ob = Out + (size_t)blk * (S_ * D_);
#pragma unroll
  for (int tn = 0; tn < 8; ++tn)
#pragma unroll
    for (int reg = 0; reg < 4; ++reg) {
      int srow = r0 + g * 4 + reg;
      Ob[(size_t)srow * D_ + tn * 16 + rl] = acc[tn][reg];
    }
}

// ---------------------------------------------------------------------------
extern "C" void kernel_launch(void* const* d_in, const int* in_sizes, int n_in,
                              void* d_out, int out_size, void* d_ws, size_t ws_size,
                              hipStream_t stream)
{
  const float* Q = (const float*)d_in[0];
  const float* K = (const float*)d_in[1];
  const float* V = (const float*)d_in[2];
  const float* W = (const float*)d_in[3];
  const float* alpha = (const float*)d_in[4];
  float* Out = (float*)d_out;

  short* VT = (short*)d_ws;                              // 32 MiB
  short* St = VT + (size_t)NBT_ * D_ * S_;               // 64 MiB
  float* dZ = (float*)(St + (size_t)NBT_ * F2_ * D_);    // 1 MiB
  short* Wt = (short*)(dZ + (size_t)NBT_ * F2_);         // 256 KiB

  hipLaunchKernelGGL(prep_w, dim3(H_), dim3(256), 0, stream, W, Wt);
  hipLaunchKernelGGL(bslh_phase1, dim3(NBT_), dim3(256), 0, stream,
                     K, V, Wt, VT, St, dZ);
  hipLaunchKernelGGL(bslh_scan, dim3(516), dim3(256), 0, stream, St, (float4*)dZ);
  hipLaunchKernelGGL(bslh_phase3, dim3(NBT_), dim3(256), 0, stream,
                     Q, K, VT, Wt, St, dZ, alpha, Out);
}